// Round 2
// baseline (2678.447 us; speedup 1.0000x reference)
//
#include <hip/hip_runtime.h>
#include <hip/hip_fp16.h>
#include <cstddef>
#include <type_traits>

#define HID 64
#define TT 64
#define NFEAT 8
#define NLAYER 5
#define TOUTC 12
#define SPB 32          // sequences per block
#define NBLK 256        // 8192 / 32
#define NTHR 256

typedef float f4 __attribute__((ext_vector_type(4)));

__device__ __forceinline__ float sigm(float x)  { return 1.0f / (1.0f + __expf(-x)); }
__device__ __forceinline__ float tanh_(float x) { return 1.0f - 2.0f / (__expf(2.0f * x) + 1.0f); }

// LDS layout (floats):
//   Wih_perm [64][256]  @ 0       (col 4*j+a  <->  original gate row a*64+j)
//   Whh_perm [64][256]  @ 16384
//   xs       [64][32]   @ 32768   (transposed: [k][s])
//   hs       [64][32]   @ 34816   (transposed: [j][s])
// total 36864 floats = 147456 B  -> 1 block/CU

template <typename ST>
__global__ __launch_bounds__(NTHR, 1)
void lstm_fused(const float* __restrict__ Xj,
                const float* __restrict__ Wih0, const float* __restrict__ Whh0,
                const float* __restrict__ bih0, const float* __restrict__ bhh0,
                const float* __restrict__ WihR, const float* __restrict__ WhhR,
                const float* __restrict__ bihR, const float* __restrict__ bhhR,
                const float* __restrict__ Wout, const float* __restrict__ bout,
                float* __restrict__ out, ST* __restrict__ ws)
{
    extern __shared__ float sm[];
    float* Wih = sm;
    float* Whh = sm + 16384;
    float* xs  = sm + 32768;
    float* hs  = sm + 34816;

    const int tid  = threadIdx.x;
    const int sgrp = tid & 7;    // 4-seq group
    const int jgrp = tid >> 3;   // hidden units jgrp and jgrp+32
    const int seq0 = blockIdx.x * SPB;
    const int col  = tid;                          // owned permuted weight column
    const int row  = (col & 3) * HID + (col >> 2); // original gate row

    float cA[4], cB[4];

    for (int layer = 0; layer < NLAYER; ++layer) {
        const int Kin = (layer == 0) ? NFEAT : HID;

        // ---- stage weights into LDS (permuted, k-major). Safe: all threads have
        // passed the post-GEMM barrier of the previous layer's last step, and the
        // activation phase never touches the W region.
        {
            const float* gWih = (layer == 0) ? (Wih0 + (size_t)row * NFEAT)
                                             : (WihR + ((size_t)(layer - 1) * 256 + row) * HID);
            const float* gWhh = (layer == 0) ? (Whh0 + (size_t)row * HID)
                                             : (WhhR + ((size_t)(layer - 1) * 256 + row) * HID);
            for (int k = 0; k < Kin; ++k) Wih[k * 256 + col] = gWih[k];
            for (int k = 0; k < HID; ++k) Whh[k * 256 + col] = gWhh[k];
        }
        float bA[4], bB[4];
        {
            const float* bi = (layer == 0) ? bih0 : (bihR + (size_t)(layer - 1) * 256);
            const float* bh = (layer == 0) ? bhh0 : (bhhR + (size_t)(layer - 1) * 256);
#pragma unroll
            for (int a = 0; a < 4; ++a) {
                int rA = a * HID + jgrp, rB = rA + 32;
                bA[a] = bi[rA] + bh[rA];
                bB[a] = bi[rB] + bh[rB];
            }
        }
        // zero h state (each thread zeroes exactly the slots it owns/writes)
        {
            f4 z = {0.f, 0.f, 0.f, 0.f};
            ((f4*)hs)[jgrp * 8 + sgrp] = z;
            ((f4*)hs)[(jgrp + 32) * 8 + sgrp] = z;
#pragma unroll
            for (int s = 0; s < 4; ++s) { cA[s] = 0.f; cB[s] = 0.f; }
        }

        for (int t = 0; t < TT; ++t) {
            // ---- stage x_t transposed into xs[k][s] ----
            if (layer == 0) {
                int s = tid >> 3, k = tid & 7;
                xs[k * 32 + s] = Xj[(size_t)(seq0 + s) * (TT * NFEAT) + t * NFEAT + k];
            } else {
                int s = tid >> 3, kc = tid & 7;
                const ST* src = ws + (size_t)(seq0 + s) * (TT * HID) + (size_t)t * HID + kc * 8;
#pragma unroll
                for (int d = 0; d < 8; ++d) {
                    float v;
                    if constexpr (std::is_same<ST, float>::value) v = src[d];
                    else                                          v = __half2float(src[d]);
                    xs[(kc * 8 + d) * 32 + s] = v;
                }
            }
            __syncthreads();   // x staged, h from previous step visible

            float accA[4][4], accB[4][4];
#pragma unroll
            for (int a = 0; a < 4; ++a)
#pragma unroll
                for (int s = 0; s < 4; ++s) { accA[a][s] = bA[a]; accB[a][s] = bB[a]; }

            // ---- x contribution ----
            if (layer == 0) {
#pragma unroll
                for (int k = 0; k < NFEAT; ++k) {
                    f4 xv = ((const f4*)xs)[k * 8 + sgrp];
                    f4 wA = ((const f4*)Wih)[k * 64 + jgrp];
                    f4 wB = ((const f4*)Wih)[k * 64 + jgrp + 32];
#pragma unroll
                    for (int a = 0; a < 4; ++a)
#pragma unroll
                        for (int s = 0; s < 4; ++s) {
                            accA[a][s] = fmaf(wA[a], xv[s], accA[a][s]);
                            accB[a][s] = fmaf(wB[a], xv[s], accB[a][s]);
                        }
                }
            } else {
#pragma unroll 4
                for (int k = 0; k < HID; ++k) {
                    f4 xv = ((const f4*)xs)[k * 8 + sgrp];
                    f4 wA = ((const f4*)Wih)[k * 64 + jgrp];
                    f4 wB = ((const f4*)Wih)[k * 64 + jgrp + 32];
#pragma unroll
                    for (int a = 0; a < 4; ++a)
#pragma unroll
                        for (int s = 0; s < 4; ++s) {
                            accA[a][s] = fmaf(wA[a], xv[s], accA[a][s]);
                            accB[a][s] = fmaf(wB[a], xv[s], accB[a][s]);
                        }
                }
            }
            // ---- h contribution ----
#pragma unroll 4
            for (int k = 0; k < HID; ++k) {
                f4 xv = ((const f4*)hs)[k * 8 + sgrp];
                f4 wA = ((const f4*)Whh)[k * 64 + jgrp];
                f4 wB = ((const f4*)Whh)[k * 64 + jgrp + 32];
#pragma unroll
                for (int a = 0; a < 4; ++a)
#pragma unroll
                    for (int s = 0; s < 4; ++s) {
                        accA[a][s] = fmaf(wA[a], xv[s], accA[a][s]);
                        accB[a][s] = fmaf(wB[a], xv[s], accB[a][s]);
                    }
            }
            __syncthreads();   // all reads of xs/hs done before we overwrite hs

            // ---- activations + state update (thread owns i,f,g,o of its 2 hidden units) ----
            float hA[4], hB[4];
#pragma unroll
            for (int s = 0; s < 4; ++s) {
                float ig = sigm(accA[0][s]);
                float fg = sigm(accA[1][s]);
                float gg = tanh_(accA[2][s]);
                float og = sigm(accA[3][s]);
                cA[s] = fg * cA[s] + ig * gg;
                hA[s] = og * tanh_(cA[s]);

                float ig2 = sigm(accB[0][s]);
                float fg2 = sigm(accB[1][s]);
                float gg2 = tanh_(accB[2][s]);
                float og2 = sigm(accB[3][s]);
                cB[s] = fg2 * cB[s] + ig2 * gg2;
                hB[s] = og2 * tanh_(cB[s]);
            }
            {
                f4 hvA = {hA[0], hA[1], hA[2], hA[3]};
                f4 hvB = {hB[0], hB[1], hB[2], hB[3]};
                ((f4*)hs)[jgrp * 8 + sgrp] = hvA;
                ((f4*)hs)[(jgrp + 32) * 8 + sgrp] = hvB;
            }
            if (layer < NLAYER - 1) {
                size_t base = (size_t)(seq0 + 4 * sgrp) * (TT * HID) + (size_t)t * HID;
#pragma unroll
                for (int s = 0; s < 4; ++s) {
                    if constexpr (std::is_same<ST, float>::value) {
                        ws[base + (size_t)s * (TT * HID) + jgrp]      = hA[s];
                        ws[base + (size_t)s * (TT * HID) + jgrp + 32] = hB[s];
                    } else {
                        ws[base + (size_t)s * (TT * HID) + jgrp]      = __float2half(hA[s]);
                        ws[base + (size_t)s * (TT * HID) + jgrp + 32] = __float2half(hB[s]);
                    }
                }
            }
            // next iteration's stage + __syncthreads makes hs writes visible
        }
    }

    __syncthreads();   // final h in hs
    // ---- output projection: 32 seqs x 12 outputs = 384 work items (grid-stride!) ----
    for (int w = tid; w < SPB * TOUTC; w += NTHR) {
        int s = w / TOUTC, o = w % TOUTC;
        float sum = bout[o];
#pragma unroll 8
        for (int j = 0; j < HID; ++j)
            sum = fmaf(Wout[o * HID + j], hs[j * 32 + s], sum);
        out[(size_t)(seq0 + s) * TOUTC + o] = sum;
    }
}

extern "C" void kernel_launch(void* const* d_in, const int* in_sizes, int n_in,
                              void* d_out, int out_size, void* d_ws, size_t ws_size,
                              hipStream_t stream)
{
    const float* Xj   = (const float*)d_in[1];   // X_joint (A_hat, X_motion unused by reference)
    const float* Wih0 = (const float*)d_in[3];
    const float* Whh0 = (const float*)d_in[4];
    const float* bih0 = (const float*)d_in[5];
    const float* bhh0 = (const float*)d_in[6];
    const float* WihR = (const float*)d_in[7];
    const float* WhhR = (const float*)d_in[8];
    const float* bihR = (const float*)d_in[9];
    const float* bhhR = (const float*)d_in[10];
    const float* Wout = (const float*)d_in[11];
    const float* bout = (const float*)d_in[12];
    float* out = (float*)d_out;

    const size_t smem = 36864 * sizeof(float);           // 147456 B
    const size_t need_f32 = (size_t)8192 * TT * HID * sizeof(float);  // 134 MB

    if (ws_size >= need_f32) {
        auto kf = lstm_fused<float>;
        (void)hipFuncSetAttribute(reinterpret_cast<const void*>(kf),
                                  hipFuncAttributeMaxDynamicSharedMemorySize, (int)smem);
        lstm_fused<float><<<NBLK, NTHR, smem, stream>>>(
            Xj, Wih0, Whh0, bih0, bhh0, WihR, WhhR, bihR, bhhR, Wout, bout,
            out, (float*)d_ws);
    } else {
        auto kh = lstm_fused<__half>;
        (void)hipFuncSetAttribute(reinterpret_cast<const void*>(kh),
                                  hipFuncAttributeMaxDynamicSharedMemorySize, (int)smem);
        lstm_fused<__half><<<NBLK, NTHR, smem, stream>>>(
            Xj, Wih0, Whh0, bih0, bhh0, WihR, WhhR, bihR, bhhR, Wout, bout,
            out, (__half*)d_ws);
    }
}

// Round 3
// 758.277 us; speedup vs baseline: 3.5323x; 3.5323x over previous
//
#include <hip/hip_runtime.h>
#include <cstddef>

#define HID 64
#define TT 64
#define NFEAT 8
#define NLAYER 5
#define TOUTC 12
#define SPB 32
#define NBLK 256
#define NTHR 256

typedef float f4 __attribute__((ext_vector_type(4)));
typedef short s8 __attribute__((ext_vector_type(8)));
typedef unsigned int u32;
typedef unsigned long long u64;

#define MFMA __builtin_amdgcn_mfma_f32_16x16x32_bf16

__device__ __forceinline__ float sigm(float x)  { return 1.0f / (1.0f + __expf(-x)); }
__device__ __forceinline__ float tanh_(float x) { return 1.0f - 2.0f / (__expf(2.0f * x) + 1.0f); }

// split fp32 -> bf16 hi (truncate) + bf16 lo (residual, truncate)
__device__ __forceinline__ void split1(float x, unsigned short& h, unsigned short& l) {
    u32 b = __float_as_uint(x);
    float xh = __uint_as_float(b & 0xFFFF0000u);
    float xl = x - xh;
    h = (unsigned short)(b >> 16);
    l = (unsigned short)(__float_as_uint(xl) >> 16);
}
__device__ __forceinline__ void split8(const float* v, s8& hi, s8& lo) {
#pragma unroll
    for (int j = 0; j < 8; ++j) {
        unsigned short h, l;
        split1(v[j], h, l);
        hi[j] = (short)h;
        lo[j] = (short)l;
    }
}

// LDS (bytes):
//   zh_hi [2][32][64] bf16 : 8192   @ 0      (XOR-swizzled: byte ^= (s&7)<<4)
//   zh_lo [2][32][64] bf16 : 8192   @ 8192
//   hs    [32][68] f32     : 8704   @ 16384  (pitch 68 to dodge proj bank conflicts)
// total 25088 B

// One LSTM layer over 64 timesteps.
// MFMA mapping (16x16x32, D=A*B): M=gate rows (4 tiles: i,f,g,o per wave's 16 hidden
// units), N=seqs (2 tiles of 16), K=[x(0..KSX*32); h(2*32)].
// A frag: lane: row=l&15 (+tile), k=8*(l>>4)+j (+32*ks). B frag: col=l&15, same k.
// C/D: col=l&15, row=4*(l>>4)+reg  [m89-verified].
template<int KSX, bool FIRST, bool LAST, bool F32WS>
__device__ __forceinline__ void run_layer(
    const float* __restrict__ Wih, const float* __restrict__ Whh,
    const float* __restrict__ bi,  const float* __restrict__ bh,
    const float* __restrict__ Xj,  void* __restrict__ wsv,
    unsigned short* zh_hi, unsigned short* zh_lo, float* hs,
    int tid, int seq0)
{
    constexpr int NKS = KSX + 2;
    constexpr bool XF = FIRST || F32WS;   // x supplied as fp32 (split hi/lo) vs bf16-only
    const int lane = tid & 63;
    const int wv   = tid >> 6;     // wave 0..3 -> hidden units [16*wv, 16*wv+16)
    const int cs   = lane & 15;
    const int rq   = lane >> 4;    // 0..3
    const int hb   = 16 * wv + 4 * rq;   // hidden base for C/D rows

    // ---- weight A-fragments (hi/lo) into VGPRs ----
    s8 Ah[4][NKS], Al[4][NKS];
#pragma unroll
    for (int a = 0; a < 4; ++a) {
        const int row = 64 * a + 16 * wv + cs;
#pragma unroll
        for (int ks = 0; ks < NKS; ++ks) {
            float v[8];
            if (ks < KSX) {
                if (FIRST) {
                    const float* p = Wih + (size_t)row * NFEAT;
#pragma unroll
                    for (int j = 0; j < 8; ++j) v[j] = (rq == 0) ? p[j] : 0.0f;
                } else {
                    const float* p = Wih + (size_t)row * HID + 32 * ks + 8 * rq;
#pragma unroll
                    for (int j = 0; j < 8; ++j) v[j] = p[j];
                }
            } else {
                const float* p = Whh + (size_t)row * HID + 32 * (ks - KSX) + 8 * rq;
#pragma unroll
                for (int j = 0; j < 8; ++j) v[j] = p[j];
            }
            split8(v, Ah[a][ks], Al[a][ks]);
        }
    }

    // ---- bias (matches C/D reg layout) ----
    f4 bias[4];
#pragma unroll
    for (int a = 0; a < 4; ++a)
#pragma unroll
        for (int r = 0; r < 4; ++r) {
            int row = 64 * a + hb + r;
            bias[a][r] = bi[row] + bh[row];
        }

    // ---- zero zh buffer 0 (both components) ----
#pragma unroll
    for (int i = 0; i < 4; ++i) {
        ((u32*)zh_hi)[tid * 4 + i] = 0u;
        ((u32*)zh_lo)[tid * 4 + i] = 0u;
    }

    f4 c0[2];
    {
        f4 z = {0.f, 0.f, 0.f, 0.f};
        c0[0] = z; c0[1] = z;
    }

    // ---- x prefetch registers ----
    f4 xf[2][2][2];   // [nt][ks][half] (fp32 path)
    s8 xs8[2][2];     // [nt][ks]      (bf16-ws path)

    auto PREF = [&](int t) {
#pragma unroll
        for (int nt = 0; nt < 2; ++nt) {
            const int seq = seq0 + cs + 16 * nt;
            if (FIRST) {
                if (rq == 0) {
                    const float* p = Xj + ((size_t)seq * TT + t) * NFEAT;
                    xf[nt][0][0] = *(const f4*)p;
                    xf[nt][0][1] = *(const f4*)(p + 4);
                } else {
                    f4 z = {0.f, 0.f, 0.f, 0.f};
                    xf[nt][0][0] = z; xf[nt][0][1] = z;
                }
            } else {
#pragma unroll
                for (int ks = 0; ks < KSX; ++ks) {
                    if (F32WS) {
                        const float* p = (const float*)wsv + ((size_t)seq * TT + t) * HID + 32 * ks + 8 * rq;
                        xf[nt][ks][0] = *(const f4*)p;
                        xf[nt][ks][1] = *(const f4*)(p + 4);
                    } else {
                        const unsigned short* p = (const unsigned short*)wsv + ((size_t)seq * TT + t) * HID + 32 * ks + 8 * rq;
                        xs8[nt][ks] = *(const s8*)p;
                    }
                }
            }
        }
    };

    PREF(0);
    __syncthreads();    // zh zero + prev-layer ws stores visible (vmcnt drained)

    int p = 0;
    for (int t = 0; t < TT; ++t) {
        // ---- x B-fragments from prefetch regs ----
        s8 bxh[2][2], bxl[2][2];
#pragma unroll
        for (int nt = 0; nt < 2; ++nt)
#pragma unroll
            for (int ks = 0; ks < KSX; ++ks) {
                if (XF) {
                    float v[8];
#pragma unroll
                    for (int j = 0; j < 4; ++j) { v[j] = xf[nt][ks][0][j]; v[4 + j] = xf[nt][ks][1][j]; }
                    split8(v, bxh[nt][ks], bxl[nt][ks]);
                } else {
                    s8 zz = {0,0,0,0,0,0,0,0};
                    bxh[nt][ks] = xs8[nt][ks];
                    bxl[nt][ks] = zz;
                }
            }

        // ---- h B-fragments from LDS (swizzled) ----
        s8 bhh[2][2], bhl[2][2];
#pragma unroll
        for (int nt = 0; nt < 2; ++nt)
#pragma unroll
            for (int kk = 0; kk < 2; ++kk) {
                const int s = cs + 16 * nt;
                int boff = p * 4096 + s * 128 + 16 * rq + 64 * kk;
                boff ^= (s & 7) << 4;
                bhh[nt][kk] = *(const s8*)((const char*)zh_hi + boff);
                bhl[nt][kk] = *(const s8*)((const char*)zh_lo + boff);
            }

        // ---- accumulators = bias ----
        f4 acc[4][2];
#pragma unroll
        for (int a = 0; a < 4; ++a) { acc[a][0] = bias[a]; acc[a][1] = bias[a]; }

        // ---- x-part MFMAs (3-product split) ----
#pragma unroll
        for (int a = 0; a < 4; ++a)
#pragma unroll
            for (int nt = 0; nt < 2; ++nt)
#pragma unroll
                for (int ks = 0; ks < KSX; ++ks) {
                    acc[a][nt] = MFMA(Ah[a][ks], bxh[nt][ks], acc[a][nt], 0, 0, 0);
                    if (XF) acc[a][nt] = MFMA(Ah[a][ks], bxl[nt][ks], acc[a][nt], 0, 0, 0);
                    acc[a][nt] = MFMA(Al[a][ks], bxh[nt][ks], acc[a][nt], 0, 0, 0);
                }

        // ---- prefetch x for t+1 (completes by next barrier's vmcnt drain) ----
        if (t + 1 < TT) PREF(t + 1);

        // ---- h-part MFMAs ----
#pragma unroll
        for (int a = 0; a < 4; ++a)
#pragma unroll
            for (int nt = 0; nt < 2; ++nt)
#pragma unroll
                for (int kk = 0; kk < 2; ++kk) {
                    acc[a][nt] = MFMA(Ah[a][KSX + kk], bhh[nt][kk], acc[a][nt], 0, 0, 0);
                    acc[a][nt] = MFMA(Ah[a][KSX + kk], bhl[nt][kk], acc[a][nt], 0, 0, 0);
                    acc[a][nt] = MFMA(Al[a][KSX + kk], bhh[nt][kk], acc[a][nt], 0, 0, 0);
                }

        // ---- activations + cell update (lane owns i,f,g,o at same (row,seq)) ----
        float hv[2][4];
#pragma unroll
        for (int nt = 0; nt < 2; ++nt)
#pragma unroll
            for (int r = 0; r < 4; ++r) {
                float ig = sigm(acc[0][nt][r]);
                float fg = sigm(acc[1][nt][r]);
                float gg = tanh_(acc[2][nt][r]);
                float og = sigm(acc[3][nt][r]);
                float cc = fg * c0[nt][r] + ig * gg;
                c0[nt][r] = cc;
                hv[nt][r] = og * tanh_(cc);
            }

        // ---- store h to ws (inter-layer) or final LDS ----
        if (!LAST) {
#pragma unroll
            for (int nt = 0; nt < 2; ++nt) {
                const int seq = seq0 + cs + 16 * nt;
                if (F32WS) {
                    f4 hvec = {hv[nt][0], hv[nt][1], hv[nt][2], hv[nt][3]};
                    *(f4*)((float*)wsv + ((size_t)seq * TT + t) * HID + hb) = hvec;
                } else {
                    u64 pk = 0;
#pragma unroll
                    for (int r = 0; r < 4; ++r) {
                        u32 b = __float_as_uint(hv[nt][r]) + 0x8000u;  // ~RNE
                        pk |= (u64)(b >> 16) << (16 * r);
                    }
                    *(u64*)((unsigned short*)wsv + ((size_t)seq * TT + t) * HID + hb) = pk;
                }
            }
        } else if (t == TT - 1) {
#pragma unroll
            for (int nt = 0; nt < 2; ++nt) {
                const int s = cs + 16 * nt;
                f4 hvec = {hv[nt][0], hv[nt][1], hv[nt][2], hv[nt][3]};
                *(f4*)(hs + s * 68 + hb) = hvec;
            }
        }

        // ---- split h and write to other zh buffer (swizzled) ----
#pragma unroll
        for (int nt = 0; nt < 2; ++nt) {
            const int s = cs + 16 * nt;
            int boff = (1 ^ p) * 4096 + s * 128 + 2 * hb;
            boff ^= (s & 7) << 4;
            u64 ph = 0, pl = 0;
#pragma unroll
            for (int r = 0; r < 4; ++r) {
                unsigned short uh, ul;
                split1(hv[nt][r], uh, ul);
                ph |= (u64)uh << (16 * r);
                pl |= (u64)ul << (16 * r);
            }
            *(u64*)((char*)zh_hi + boff) = ph;
            *(u64*)((char*)zh_lo + boff) = pl;
        }

        __syncthreads();   // drains vmcnt (prefetch loads + ws stores) and lgkmcnt
        p ^= 1;
    }
}

template<bool F32WS>
__global__ __launch_bounds__(NTHR, 1)
void lstm_mfma(const float* __restrict__ Xj,
               const float* __restrict__ Wih0, const float* __restrict__ Whh0,
               const float* __restrict__ bih0, const float* __restrict__ bhh0,
               const float* __restrict__ WihR, const float* __restrict__ WhhR,
               const float* __restrict__ bihR, const float* __restrict__ bhhR,
               const float* __restrict__ Wout, const float* __restrict__ bout,
               float* __restrict__ out, void* __restrict__ wsv)
{
    __shared__ char smraw[25088];
    unsigned short* zh_hi = (unsigned short*)smraw;
    unsigned short* zh_lo = (unsigned short*)(smraw + 8192);
    float* hs = (float*)(smraw + 16384);

    const int tid  = threadIdx.x;
    const int seq0 = blockIdx.x * SPB;

    run_layer<1, true,  false, F32WS>(Wih0, Whh0, bih0, bhh0, Xj, wsv, zh_hi, zh_lo, hs, tid, seq0);
#pragma unroll 1
    for (int l = 0; l < 3; ++l)
        run_layer<2, false, false, F32WS>(WihR + (size_t)l * 256 * HID, WhhR + (size_t)l * 256 * HID,
                                          bihR + (size_t)l * 256, bhhR + (size_t)l * 256,
                                          nullptr, wsv, zh_hi, zh_lo, hs, tid, seq0);
    run_layer<2, false, true,  F32WS>(WihR + (size_t)3 * 256 * HID, WhhR + (size_t)3 * 256 * HID,
                                      bihR + (size_t)3 * 256, bhhR + (size_t)3 * 256,
                                      nullptr, wsv, zh_hi, zh_lo, hs, tid, seq0);

    __syncthreads();
    // ---- output projection: 32 seqs x 12 outs ----
    for (int it = tid; it < SPB * TOUTC; it += NTHR) {
        int s = it / TOUTC, o = it % TOUTC;
        float sum = bout[o];
#pragma unroll 8
        for (int j = 0; j < HID; ++j)
            sum = fmaf(Wout[o * HID + j], hs[s * 68 + j], sum);
        out[(size_t)(seq0 + s) * TOUTC + o] = sum;
    }
}

extern "C" void kernel_launch(void* const* d_in, const int* in_sizes, int n_in,
                              void* d_out, int out_size, void* d_ws, size_t ws_size,
                              hipStream_t stream)
{
    const float* Xj   = (const float*)d_in[1];
    const float* Wih0 = (const float*)d_in[3];
    const float* Whh0 = (const float*)d_in[4];
    const float* bih0 = (const float*)d_in[5];
    const float* bhh0 = (const float*)d_in[6];
    const float* WihR = (const float*)d_in[7];
    const float* WhhR = (const float*)d_in[8];
    const float* bihR = (const float*)d_in[9];
    const float* bhhR = (const float*)d_in[10];
    const float* Wout = (const float*)d_in[11];
    const float* bout = (const float*)d_in[12];
    float* out = (float*)d_out;

    const size_t need_f32 = (size_t)8192 * TT * HID * sizeof(float);  // 134 MB

    if (ws_size >= need_f32) {
        lstm_mfma<true><<<NBLK, NTHR, 0, stream>>>(Xj, Wih0, Whh0, bih0, bhh0,
                                                   WihR, WhhR, bihR, bhhR,
                                                   Wout, bout, out, d_ws);
    } else {
        lstm_mfma<false><<<NBLK, NTHR, 0, stream>>>(Xj, Wih0, Whh0, bih0, bhh0,
                                                    WihR, WhhR, bihR, bhhR,
                                                    Wout, bout, out, d_ws);
    }
}

// Round 4
// 663.576 us; speedup vs baseline: 4.0364x; 1.1427x over previous
//
#include <hip/hip_runtime.h>
#include <cstddef>

#define HID 64
#define TT 64
#define NFEAT 8
#define NLAYER 5
#define TOUTC 12
#define SPB 16
#define NBLK 512
#define NTHR 256

typedef float f4 __attribute__((ext_vector_type(4)));
typedef short s8 __attribute__((ext_vector_type(8)));
typedef unsigned int u32;
typedef unsigned long long u64;

#define MFMA __builtin_amdgcn_mfma_f32_16x16x32_bf16

__device__ __forceinline__ float sigm(float x)  { return 1.0f / (1.0f + __expf(-x)); }
__device__ __forceinline__ float tanh_(float x) { return 1.0f - 2.0f / (__expf(2.0f * x) + 1.0f); }

// split fp32 -> bf16 hi (truncate) + bf16 lo (residual, truncate)
__device__ __forceinline__ void split1(float x, unsigned short& h, unsigned short& l) {
    u32 b = __float_as_uint(x);
    float xh = __uint_as_float(b & 0xFFFF0000u);
    float xl = x - xh;
    h = (unsigned short)(b >> 16);
    l = (unsigned short)(__float_as_uint(xl) >> 16);
}
__device__ __forceinline__ void split8(const float* v, s8& hi, s8& lo) {
#pragma unroll
    for (int j = 0; j < 8; ++j) {
        unsigned short h, l;
        split1(v[j], h, l);
        hi[j] = (short)h;
        lo[j] = (short)l;
    }
}

// LDS (bytes):
//   zh_hi [2][16][64] bf16 : 4096 @ 0      (XOR-swizzled: byte ^= (s&7)<<4)
//   zh_lo [2][16][64] bf16 : 4096 @ 4096
//   hs    [16][68] f32     : 4352 @ 8192
// total 12544 B -> 2 blocks/CU fine
//
// ws layout (HILO): bf16 [seq][t][2][HID]  (comp 0 = hi, comp 1 = lo), 134 MB
//          (!HILO): bf16 [seq][t][HID] (RNE hi only), 67 MB
//
// MFMA mapping (16x16x32): M = gate rows (4 tiles i,f,g,o x wave's 16 hidden),
// N = 16 seqs, K = [x (KSX*32); h (2*32)].
// A frag: row=l&15, k=8*(l>>4)+j. B frag: col=l&15, same k. C/D: col=l&15, row=4*(l>>4)+r.
template<int KSX, bool FIRST, bool LAST, bool HILO>
__device__ __forceinline__ void run_layer(
    const float* __restrict__ Wih, const float* __restrict__ Whh,
    const float* __restrict__ bi,  const float* __restrict__ bh,
    const float* __restrict__ Xj,  unsigned short* __restrict__ ws,
    unsigned short* zh_hi, unsigned short* zh_lo, float* hs,
    int tid, int seq0)
{
    constexpr int NKS = KSX + 2;
    constexpr int WST = HID * (HILO ? 2 : 1);   // shorts per (seq,t)
    constexpr bool XLO = FIRST || HILO;         // have a lo component for x
    const int lane = tid & 63;
    const int wv   = tid >> 6;           // wave -> hidden units [16wv, 16wv+16)
    const int cs   = lane & 15;          // seq column
    const int rq   = lane >> 4;          // 0..3
    const int hb   = 16 * wv + 4 * rq;   // C/D row base (hidden unit)
    const int seq  = seq0 + cs;

    // ---- weight A-fragments (hi/lo) into regs ----
    s8 Ah[4][NKS], Al[4][NKS];
#pragma unroll
    for (int a = 0; a < 4; ++a) {
        const int row = 64 * a + 16 * wv + cs;
#pragma unroll
        for (int ks = 0; ks < NKS; ++ks) {
            float v[8];
            if (ks < KSX) {
                if (FIRST) {
                    const float* p = Wih + (size_t)row * NFEAT;
#pragma unroll
                    for (int j = 0; j < 8; ++j) v[j] = (rq == 0) ? p[j] : 0.0f;
                } else {
                    const float* p = Wih + (size_t)row * HID + 32 * ks + 8 * rq;
#pragma unroll
                    for (int j = 0; j < 8; ++j) v[j] = p[j];
                }
            } else {
                const float* p = Whh + (size_t)row * HID + 32 * (ks - KSX) + 8 * rq;
#pragma unroll
                for (int j = 0; j < 8; ++j) v[j] = p[j];
            }
            split8(v, Ah[a][ks], Al[a][ks]);
        }
    }

    // ---- bias (C/D layout) ----
    f4 bias[4];
#pragma unroll
    for (int a = 0; a < 4; ++a)
#pragma unroll
        for (int r = 0; r < 4; ++r) {
            int row = 64 * a + hb + r;
            bias[a][r] = bi[row] + bh[row];
        }

    // ---- zero zh buffers (4096 B each = 1024 u32 = 256 thr * 4) ----
#pragma unroll
    for (int i = 0; i < 4; ++i) {
        ((u32*)zh_hi)[tid * 4 + i] = 0u;
        ((u32*)zh_lo)[tid * 4 + i] = 0u;
    }

    f4 c0 = {0.f, 0.f, 0.f, 0.f};

    // ---- x prefetch regs ----
    f4 xf[2];             // FIRST (fp32 x, rq==0 lanes)
    s8 xh8[2], xl8[2];    // recurrent layers (pre-split bf16)

    auto PREF = [&](int t) {
        if (FIRST) {
            if (rq == 0) {
                const float* p = Xj + ((size_t)seq * TT + t) * NFEAT;
                xf[0] = *(const f4*)p;
                xf[1] = *(const f4*)(p + 4);
            } else {
                f4 z = {0.f, 0.f, 0.f, 0.f};
                xf[0] = z; xf[1] = z;
            }
        } else {
            const unsigned short* p = ws + ((size_t)seq * TT + t) * WST;
#pragma unroll
            for (int ks = 0; ks < KSX; ++ks) {
                xh8[ks] = *(const s8*)(p + 32 * ks + 8 * rq);
                if (HILO) xl8[ks] = *(const s8*)(p + HID + 32 * ks + 8 * rq);
            }
        }
    };

    PREF(0);
    __syncthreads();   // zh zeroed; prev-layer ws stores drained at its last barrier

    int p = 0;
    for (int t = 0; t < TT; ++t) {
        // ---- x B-fragments ----
        s8 bxh[KSX], bxl[KSX];
        if (FIRST) {
            float v[8];
#pragma unroll
            for (int j = 0; j < 4; ++j) { v[j] = xf[0][j]; v[4 + j] = xf[1][j]; }
            split8(v, bxh[0], bxl[0]);
        } else {
#pragma unroll
            for (int ks = 0; ks < KSX; ++ks) {
                bxh[ks] = xh8[ks];
                if (HILO) bxl[ks] = xl8[ks];
            }
        }

        // ---- h B-fragments from LDS (swizzled) ----
        s8 bhh[2], bhl[2];
#pragma unroll
        for (int kk = 0; kk < 2; ++kk) {
            int boff = p * 2048 + cs * 128 + 16 * rq + 64 * kk;
            boff ^= (cs & 7) << 4;
            bhh[kk] = *(const s8*)((const char*)zh_hi + boff);
            bhl[kk] = *(const s8*)((const char*)zh_lo + boff);
        }

        // ---- MFMA: two independent chains per gate ----
        f4 c1[4], c2[4];
#pragma unroll
        for (int a = 0; a < 4; ++a) {
            c1[a] = bias[a];
            f4 z = {0.f, 0.f, 0.f, 0.f};
            c2[a] = z;
        }
#pragma unroll
        for (int a = 0; a < 4; ++a)
#pragma unroll
            for (int ks = 0; ks < KSX; ++ks) {
                c1[a] = MFMA(Ah[a][ks], bxh[ks], c1[a], 0, 0, 0);
                c2[a] = MFMA(Al[a][ks], bxh[ks], c2[a], 0, 0, 0);
                if (XLO) c2[a] = MFMA(Ah[a][ks], bxl[ks], c2[a], 0, 0, 0);
            }

        if (t + 1 < TT) PREF(t + 1);   // overlap with h-MFMAs

#pragma unroll
        for (int a = 0; a < 4; ++a)
#pragma unroll
            for (int kk = 0; kk < 2; ++kk) {
                c1[a] = MFMA(Ah[a][KSX + kk], bhh[kk], c1[a], 0, 0, 0);
                c2[a] = MFMA(Al[a][KSX + kk], bhh[kk], c2[a], 0, 0, 0);
                c2[a] = MFMA(Ah[a][KSX + kk], bhl[kk], c2[a], 0, 0, 0);
            }

        // ---- activations + cell update ----
        float hv[4];
#pragma unroll
        for (int r = 0; r < 4; ++r) {
            float ig = sigm(c1[0][r] + c2[0][r]);
            float fg = sigm(c1[1][r] + c2[1][r]);
            float gg = tanh_(c1[2][r] + c2[2][r]);
            float og = sigm(c1[3][r] + c2[3][r]);
            float cc = fg * c0[r] + ig * gg;
            c0[r] = cc;
            hv[r] = og * tanh_(cc);
        }

        // ---- split h once; reuse packs for both LDS and ws ----
        u64 ph = 0, pl = 0;
#pragma unroll
        for (int r = 0; r < 4; ++r) {
            unsigned short uh, ul;
            split1(hv[r], uh, ul);
            ph |= (u64)uh << (16 * r);
            pl |= (u64)ul << (16 * r);
        }
        {
            int wo = (1 ^ p) * 2048 + cs * 128 + 2 * hb;
            wo ^= (cs & 7) << 4;
            *(u64*)((char*)zh_hi + wo) = ph;
            *(u64*)((char*)zh_lo + wo) = pl;
        }
        if (!LAST) {
            unsigned short* q = ws + ((size_t)seq * TT + t) * WST + hb;
            if (HILO) {
                *(u64*)q = ph;
                *(u64*)(q + HID) = pl;
            } else {
                u64 pr = 0;
#pragma unroll
                for (int r = 0; r < 4; ++r) {
                    u32 b = __float_as_uint(hv[r]) + 0x8000u;  // ~RNE hi
                    pr |= (u64)(b >> 16) << (16 * r);
                }
                *(u64*)q = pr;
            }
        } else if (t == TT - 1) {
            f4 hvec = {hv[0], hv[1], hv[2], hv[3]};
            *(f4*)(hs + cs * 68 + hb) = hvec;
        }

        __syncthreads();
        p ^= 1;
    }
}

template<bool HILO>
__global__ __launch_bounds__(NTHR, 2)
void lstm_mfma(const float* __restrict__ Xj,
               const float* __restrict__ Wih0, const float* __restrict__ Whh0,
               const float* __restrict__ bih0, const float* __restrict__ bhh0,
               const float* __restrict__ WihR, const float* __restrict__ WhhR,
               const float* __restrict__ bihR, const float* __restrict__ bhhR,
               const float* __restrict__ Wout, const float* __restrict__ bout,
               float* __restrict__ out, unsigned short* __restrict__ ws)
{
    __shared__ char smraw[12544];
    unsigned short* zh_hi = (unsigned short*)smraw;
    unsigned short* zh_lo = (unsigned short*)(smraw + 4096);
    float* hs = (float*)(smraw + 8192);

    const int tid  = threadIdx.x;
    const int seq0 = blockIdx.x * SPB;

    run_layer<1, true,  false, HILO>(Wih0, Whh0, bih0, bhh0, Xj, ws, zh_hi, zh_lo, hs, tid, seq0);
#pragma unroll 1
    for (int l = 0; l < 3; ++l)
        run_layer<2, false, false, HILO>(WihR + (size_t)l * 256 * HID, WhhR + (size_t)l * 256 * HID,
                                         bihR + (size_t)l * 256, bhhR + (size_t)l * 256,
                                         nullptr, ws, zh_hi, zh_lo, hs, tid, seq0);
    run_layer<2, false, true,  HILO>(WihR + (size_t)3 * 256 * HID, WhhR + (size_t)3 * 256 * HID,
                                     bihR + (size_t)3 * 256, bhhR + (size_t)3 * 256,
                                     nullptr, ws, zh_hi, zh_lo, hs, tid, seq0);

    __syncthreads();
    // ---- output projection: 16 seqs x 12 outs = 192 items ----
    for (int it = tid; it < SPB * TOUTC; it += NTHR) {
        int s = it / TOUTC, o = it % TOUTC;
        float sum = bout[o];
#pragma unroll 8
        for (int j = 0; j < HID; ++j)
            sum = fmaf(Wout[o * HID + j], hs[s * 68 + j], sum);
        out[(size_t)(seq0 + s) * TOUTC + o] = sum;
    }
}

extern "C" void kernel_launch(void* const* d_in, const int* in_sizes, int n_in,
                              void* d_out, int out_size, void* d_ws, size_t ws_size,
                              hipStream_t stream)
{
    const float* Xj   = (const float*)d_in[1];
    const float* Wih0 = (const float*)d_in[3];
    const float* Whh0 = (const float*)d_in[4];
    const float* bih0 = (const float*)d_in[5];
    const float* bhh0 = (const float*)d_in[6];
    const float* WihR = (const float*)d_in[7];
    const float* WhhR = (const float*)d_in[8];
    const float* bihR = (const float*)d_in[9];
    const float* bhhR = (const float*)d_in[10];
    const float* Wout = (const float*)d_in[11];
    const float* bout = (const float*)d_in[12];
    float* out = (float*)d_out;

    const size_t need_hilo = (size_t)8192 * TT * 2 * HID * sizeof(unsigned short); // 134 MB

    if (ws_size >= need_hilo) {
        lstm_mfma<true><<<NBLK, NTHR, 0, stream>>>(Xj, Wih0, Whh0, bih0, bhh0,
                                                   WihR, WhhR, bihR, bhhR,
                                                   Wout, bout, out, (unsigned short*)d_ws);
    } else {
        lstm_mfma<false><<<NBLK, NTHR, 0, stream>>>(Xj, Wih0, Whh0, bih0, bhh0,
                                                    WihR, WhhR, bihR, bhhR,
                                                    Wout, bout, out, (unsigned short*)d_ws);
    }
}